// Round 1
// baseline (2556.562 us; speedup 1.0000x reference)
//
#include <hip/hip_runtime.h>

// GatingNetwork: h = x@fc_w^T + b; BatchNorm(batch axis); ReLU;
// capsule u = h @ W_caps[e]; squash; 3-iter dynamic routing; logits; softmax.
// B=131072, D_IN=HID=256, E=4, CAP=16.

#define BATCH   131072
#define INV_B   (1.0f / 131072.0f)

// ---------------------------------------------------------------------------
// Kernel 1: fp32 tiled GEMM  h[b,j] = sum_d x[b,d]*w[j,d] + bias[j]
// 128x128 tile, 256 threads, 8x8 microtile. Also accumulates per-channel
// sum / sum-of-squares into global stats via LDS partials + atomics.
// ---------------------------------------------------------------------------
__global__ __launch_bounds__(256) void k_gemm(
    const float* __restrict__ x, const float* __restrict__ w,
    const float* __restrict__ bias, float* __restrict__ h,
    float* __restrict__ gsum, float* __restrict__ gsq)
{
    __shared__ float Xs[16][132];
    __shared__ float Ws[16][132];
    __shared__ float csum[128];
    __shared__ float csq[128];

    const int t  = threadIdx.x;
    const int bm = ((int)blockIdx.x >> 1) * 128;
    const int bn = ((int)blockIdx.x & 1) * 128;

    const int lrow = t >> 1;          // 0..127
    const int lk8  = (t & 1) * 8;     // 0 or 8
    const int tm   = t & 15;          // row group
    const int tn   = t >> 4;          // col group

    float acc[8][8];
#pragma unroll
    for (int i = 0; i < 8; ++i)
#pragma unroll
        for (int j = 0; j < 8; ++j) acc[i][j] = 0.f;

    const float* xp = x + (size_t)(bm + lrow) * 256 + lk8;
    const float* wp = w + (size_t)(bn + lrow) * 256 + lk8;

    for (int k0 = 0; k0 < 256; k0 += 16) {
        float4 xa = *(const float4*)(xp + k0);
        float4 xb = *(const float4*)(xp + k0 + 4);
        float4 wa = *(const float4*)(wp + k0);
        float4 wb = *(const float4*)(wp + k0 + 4);
        __syncthreads();
        Xs[lk8+0][lrow]=xa.x; Xs[lk8+1][lrow]=xa.y; Xs[lk8+2][lrow]=xa.z; Xs[lk8+3][lrow]=xa.w;
        Xs[lk8+4][lrow]=xb.x; Xs[lk8+5][lrow]=xb.y; Xs[lk8+6][lrow]=xb.z; Xs[lk8+7][lrow]=xb.w;
        Ws[lk8+0][lrow]=wa.x; Ws[lk8+1][lrow]=wa.y; Ws[lk8+2][lrow]=wa.z; Ws[lk8+3][lrow]=wa.w;
        Ws[lk8+4][lrow]=wb.x; Ws[lk8+5][lrow]=wb.y; Ws[lk8+6][lrow]=wb.z; Ws[lk8+7][lrow]=wb.w;
        __syncthreads();
#pragma unroll
        for (int k = 0; k < 16; ++k) {
            float4 a0 = *(const float4*)&Xs[k][tm*8];
            float4 a1 = *(const float4*)&Xs[k][tm*8+4];
            float4 b0 = *(const float4*)&Ws[k][tn*8];
            float4 b1 = *(const float4*)&Ws[k][tn*8+4];
            float av[8] = {a0.x,a0.y,a0.z,a0.w,a1.x,a1.y,a1.z,a1.w};
            float bv[8] = {b0.x,b0.y,b0.z,b0.w,b1.x,b1.y,b1.z,b1.w};
#pragma unroll
            for (int i = 0; i < 8; ++i)
#pragma unroll
                for (int j = 0; j < 8; ++j)
                    acc[i][j] = fmaf(av[i], bv[j], acc[i][j]);
        }
    }

    if (t < 128) { csum[t] = 0.f; csq[t] = 0.f; }

    float bb[8];
#pragma unroll
    for (int j = 0; j < 8; ++j) bb[j] = bias[bn + tn*8 + j];

    float lsum[8], lsq[8];
#pragma unroll
    for (int j = 0; j < 8; ++j) { lsum[j] = 0.f; lsq[j] = 0.f; }

    __syncthreads();

#pragma unroll
    for (int i = 0; i < 8; ++i) {
        float hv[8];
#pragma unroll
        for (int j = 0; j < 8; ++j) {
            hv[j] = acc[i][j] + bb[j];
            lsum[j] += hv[j];
            lsq[j]   = fmaf(hv[j], hv[j], lsq[j]);
        }
        float* hp = h + (size_t)(bm + tm*8 + i) * 256 + (bn + tn*8);
        *(float4*)(hp)     = make_float4(hv[0],hv[1],hv[2],hv[3]);
        *(float4*)(hp + 4) = make_float4(hv[4],hv[5],hv[6],hv[7]);
    }
#pragma unroll
    for (int j = 0; j < 8; ++j) {
        atomicAdd(&csum[tn*8+j], lsum[j]);
        atomicAdd(&csq[tn*8+j],  lsq[j]);
    }
    __syncthreads();
    if (t < 128) {
        atomicAdd(&gsum[bn + t], csum[t]);
        atomicAdd(&gsq[bn + t],  csq[t]);
    }
}

// ---------------------------------------------------------------------------
// Kernel 2: finalize BN stats -> per-channel scale a, shift c
// h_norm = h*a + c  with a = gamma*rstd, c = beta - mean*a
// ---------------------------------------------------------------------------
__global__ void k_stats(const float* __restrict__ gsum, const float* __restrict__ gsq,
                        const float* __restrict__ gamma, const float* __restrict__ beta,
                        float* __restrict__ ab)
{
    int j = threadIdx.x;
    float mean = gsum[j] * INV_B;
    float var  = gsq[j] * INV_B - mean * mean;
    float rstd = rsqrtf(var + 1e-5f);
    float a = gamma[j] * rstd;
    ab[j]       = a;
    ab[256 + j] = beta[j] - mean * a;
}

// ---------------------------------------------------------------------------
// Kernel 3: fused BN + ReLU + capsule projection + routing + output softmax.
// 256 threads = 4 waves. Each wave: 16 rows in 4 batches of 4.
// Lane l = (e = l>>4, o = l&15). u[e,o] = sum_d hn[d] * Wc[e,d,o].
// W_caps staged in LDS in two 128-d halves (32KB) to stay under 64KB LDS.
// squash/softmax via __shfl_xor reductions (16-wide over o, cross-group over e).
// ---------------------------------------------------------------------------
__global__ __launch_bounds__(256) void k_caps(
    const float* __restrict__ h, const float* __restrict__ ab,
    const float* __restrict__ wc, const float* __restrict__ ow_g,
    const float* __restrict__ ob_g, float* __restrict__ out)
{
    __shared__ float Wl[128 * 64];     // Wl[dd*64 + e*16 + o], 32KB
    __shared__ float hs[4][4][256];    // per-wave 4-row h buffer, 16KB

    const int t   = threadIdx.x;
    const int wid = t >> 6;
    const int l   = t & 63;
    const int e   = l >> 4;
    const int o   = l & 15;

    float ow[4], ob[4];
#pragma unroll
    for (int k = 0; k < 4; ++k) { ow[k] = ow_g[k*16 + o]; ob[k] = ob_g[k]; }

    const float4 a4 = *(const float4*)(ab + l*4);
    const float4 c4 = *(const float4*)(ab + 256 + l*4);

    const int gw = (int)blockIdx.x * 4 + wid;   // 8192 waves, 16 rows each

    for (int batch = 0; batch < 4; ++batch) {
        const int row0 = gw * 16 + batch * 4;

        // load 4 rows, apply BN + ReLU, park in LDS
#pragma unroll
        for (int r = 0; r < 4; ++r) {
            float4 hv = *(const float4*)(h + (size_t)(row0 + r) * 256 + l*4);
            float4 hn;
            hn.x = fmaxf(fmaf(hv.x, a4.x, c4.x), 0.f);
            hn.y = fmaxf(fmaf(hv.y, a4.y, c4.y), 0.f);
            hn.z = fmaxf(fmaf(hv.z, a4.z, c4.z), 0.f);
            hn.w = fmaxf(fmaf(hv.w, a4.w, c4.w), 0.f);
            *(float4*)&hs[wid][r][l*4] = hn;
        }

        float u[4] = {0.f, 0.f, 0.f, 0.f};

        for (int half = 0; half < 2; ++half) {
            __syncthreads();   // prior readers of Wl done; hs writes ordered
            // stage 128 d's of W_caps: Wc flat = e*4096 + d*16 + o
#pragma unroll
            for (int it = 0; it < 8; ++it) {
                int idx = it*1024 + t*4;        // 0..8191
                int ee  = idx >> 11;
                int r2  = idx & 2047;
                int dd  = r2 >> 4;
                int oo  = r2 & 15;
                float4 v = *(const float4*)(wc + ee*4096 + half*2048 + r2);
                float* dst = &Wl[dd*64 + ee*16 + oo];
                dst[0]=v.x; dst[1]=v.y; dst[2]=v.z; dst[3]=v.w;
            }
            __syncthreads();

            for (int dd = 0; dd < 128; dd += 4) {
                float w0 = Wl[(dd+0)*64 + l];
                float w1 = Wl[(dd+1)*64 + l];
                float w2 = Wl[(dd+2)*64 + l];
                float w3 = Wl[(dd+3)*64 + l];
#pragma unroll
                for (int r = 0; r < 4; ++r) {
                    float4 h4 = *(const float4*)&hs[wid][r][half*128 + dd];
                    u[r] = fmaf(h4.x, w0, u[r]);
                    u[r] = fmaf(h4.y, w1, u[r]);
                    u[r] = fmaf(h4.z, w2, u[r]);
                    u[r] = fmaf(h4.w, w3, u[r]);
                }
            }
        }

        // routing + output for the 4 rows (register-resident, shuffle reductions)
#pragma unroll
        for (int r = 0; r < 4; ++r) {
            float uv = u[r];
            // squash(u)
            float n2 = uv * uv;
            n2 += __shfl_xor(n2, 1); n2 += __shfl_xor(n2, 2);
            n2 += __shfl_xor(n2, 4); n2 += __shfl_xor(n2, 8);
            float nrm = sqrtf(n2);
            float uh  = (nrm / ((1.f + n2) * (nrm + 1e-8f))) * uv;

            float b = 0.f, vv = 0.f;
            for (int it3 = 0; it3 < 3; ++it3) {
                // softmax over experts (cross-group: lanes l^16, l^32)
                float bmax = b;
                bmax = fmaxf(bmax, __shfl_xor(bmax, 16));
                bmax = fmaxf(bmax, __shfl_xor(bmax, 32));
                float eb = __expf(b - bmax);
                float es = eb;
                es += __shfl_xor(es, 16);
                es += __shfl_xor(es, 32);
                float c = eb / es;
                // s = c * u_hat ; v = squash(s)
                float sv  = c * uh;
                float sn2 = sv * sv;
                sn2 += __shfl_xor(sn2, 1); sn2 += __shfl_xor(sn2, 2);
                sn2 += __shfl_xor(sn2, 4); sn2 += __shfl_xor(sn2, 8);
                float snrm = sqrtf(sn2);
                vv = (snrm / ((1.f + sn2) * (snrm + 1e-8f))) * sv;
                if (it3 < 2) {
                    float dp = uh * vv;
                    dp += __shfl_xor(dp, 1); dp += __shfl_xor(dp, 2);
                    dp += __shfl_xor(dp, 4); dp += __shfl_xor(dp, 8);
                    b += dp;
                }
            }
            // logits[e][k] = sum_c v[e][c]*out_w[k][c] + out_b[k]; softmax over k
            float p0 = vv * ow[0], p1 = vv * ow[1], p2 = vv * ow[2], p3 = vv * ow[3];
            p0 += __shfl_xor(p0,1); p0 += __shfl_xor(p0,2); p0 += __shfl_xor(p0,4); p0 += __shfl_xor(p0,8);
            p1 += __shfl_xor(p1,1); p1 += __shfl_xor(p1,2); p1 += __shfl_xor(p1,4); p1 += __shfl_xor(p1,8);
            p2 += __shfl_xor(p2,1); p2 += __shfl_xor(p2,2); p2 += __shfl_xor(p2,4); p2 += __shfl_xor(p2,8);
            p3 += __shfl_xor(p3,1); p3 += __shfl_xor(p3,2); p3 += __shfl_xor(p3,4); p3 += __shfl_xor(p3,8);
            p0 += ob[0]; p1 += ob[1]; p2 += ob[2]; p3 += ob[3];
            float mx = fmaxf(fmaxf(p0, p1), fmaxf(p2, p3));
            float e0 = __expf(p0 - mx), e1 = __expf(p1 - mx);
            float e2 = __expf(p2 - mx), e3 = __expf(p3 - mx);
            float inv = 1.f / (e0 + e1 + e2 + e3);
            if (o < 4) {
                float pr = (o == 0) ? e0 : ((o == 1) ? e1 : ((o == 2) ? e2 : e3));
                out[(size_t)(row0 + r) * 16 + e * 4 + o] = pr * inv;
            }
        }
    }
}

// ---------------------------------------------------------------------------
extern "C" void kernel_launch(void* const* d_in, const int* in_sizes, int n_in,
                              void* d_out, int out_size, void* d_ws, size_t ws_size,
                              hipStream_t stream)
{
    const float* x     = (const float*)d_in[0];
    const float* fc_w  = (const float*)d_in[1];
    const float* fc_b  = (const float*)d_in[2];
    const float* gamma = (const float*)d_in[3];
    const float* beta  = (const float*)d_in[4];
    const float* wc    = (const float*)d_in[5];
    const float* ow    = (const float*)d_in[6];
    const float* ob    = (const float*)d_in[7];
    float* out = (float*)d_out;

    float* gsum = (float*)d_ws;                 // [256]
    float* gsq  = gsum + 256;                   // [256]
    float* ab   = gsum + 512;                   // [512] scale|shift
    float* h    = (float*)((char*)d_ws + 4096); // [131072*256] fp32 = 134MB

    hipMemsetAsync(d_ws, 0, 2048, stream);      // zero gsum/gsq each call

    k_gemm <<<dim3(2048), dim3(256), 0, stream>>>(x, fc_w, fc_b, h, gsum, gsq);
    k_stats<<<dim3(1),    dim3(256), 0, stream>>>(gsum, gsq, gamma, beta, ab);
    k_caps <<<dim3(2048), dim3(256), 0, stream>>>(h, ab, wc, ow, ob, out);
}

// Round 2
// 471.266 us; speedup vs baseline: 5.4249x; 5.4249x over previous
//
#include <hip/hip_runtime.h>

// GatingNetwork: h = x@fc_w^T + b; BatchNorm(batch axis); ReLU;
// capsule u = h @ W_caps[e]; squash; 3-iter dynamic routing; logits; softmax.
// B=131072, D_IN=HID=256, E=4, CAP=16.

#define BATCH   131072
#define INV_B   (1.0f / 131072.0f)

// ---------------------------------------------------------------------------
// Kernel 1: fp32 tiled GEMM  h[b,j] = sum_d x[b,d]*w[j,d] + bias[j]
// 128x128 tile, 256 threads, 8x8 microtile. Also accumulates per-channel
// sum / sum-of-squares into global stats via LDS partials + atomics.
// (unchanged from R1 — measured ~220us real-run; R3 target)
// ---------------------------------------------------------------------------
__global__ __launch_bounds__(256) void k_gemm(
    const float* __restrict__ x, const float* __restrict__ w,
    const float* __restrict__ bias, float* __restrict__ h,
    float* __restrict__ gsum, float* __restrict__ gsq)
{
    __shared__ float Xs[16][132];
    __shared__ float Ws[16][132];
    __shared__ float csum[128];
    __shared__ float csq[128];

    const int t  = threadIdx.x;
    const int bm = ((int)blockIdx.x >> 1) * 128;
    const int bn = ((int)blockIdx.x & 1) * 128;

    const int lrow = t >> 1;          // 0..127
    const int lk8  = (t & 1) * 8;     // 0 or 8
    const int tm   = t & 15;          // row group
    const int tn   = t >> 4;          // col group

    float acc[8][8];
#pragma unroll
    for (int i = 0; i < 8; ++i)
#pragma unroll
        for (int j = 0; j < 8; ++j) acc[i][j] = 0.f;

    const float* xp = x + (size_t)(bm + lrow) * 256 + lk8;
    const float* wp = w + (size_t)(bn + lrow) * 256 + lk8;

    for (int k0 = 0; k0 < 256; k0 += 16) {
        float4 xa = *(const float4*)(xp + k0);
        float4 xb = *(const float4*)(xp + k0 + 4);
        float4 wa = *(const float4*)(wp + k0);
        float4 wb = *(const float4*)(wp + k0 + 4);
        __syncthreads();
        Xs[lk8+0][lrow]=xa.x; Xs[lk8+1][lrow]=xa.y; Xs[lk8+2][lrow]=xa.z; Xs[lk8+3][lrow]=xa.w;
        Xs[lk8+4][lrow]=xb.x; Xs[lk8+5][lrow]=xb.y; Xs[lk8+6][lrow]=xb.z; Xs[lk8+7][lrow]=xb.w;
        Ws[lk8+0][lrow]=wa.x; Ws[lk8+1][lrow]=wa.y; Ws[lk8+2][lrow]=wa.z; Ws[lk8+3][lrow]=wa.w;
        Ws[lk8+4][lrow]=wb.x; Ws[lk8+5][lrow]=wb.y; Ws[lk8+6][lrow]=wb.z; Ws[lk8+7][lrow]=wb.w;
        __syncthreads();
#pragma unroll
        for (int k = 0; k < 16; ++k) {
            float4 a0 = *(const float4*)&Xs[k][tm*8];
            float4 a1 = *(const float4*)&Xs[k][tm*8+4];
            float4 b0 = *(const float4*)&Ws[k][tn*8];
            float4 b1 = *(const float4*)&Ws[k][tn*8+4];
            float av[8] = {a0.x,a0.y,a0.z,a0.w,a1.x,a1.y,a1.z,a1.w};
            float bv[8] = {b0.x,b0.y,b0.z,b0.w,b1.x,b1.y,b1.z,b1.w};
#pragma unroll
            for (int i = 0; i < 8; ++i)
#pragma unroll
                for (int j = 0; j < 8; ++j)
                    acc[i][j] = fmaf(av[i], bv[j], acc[i][j]);
        }
    }

    if (t < 128) { csum[t] = 0.f; csq[t] = 0.f; }

    float bb[8];
#pragma unroll
    for (int j = 0; j < 8; ++j) bb[j] = bias[bn + tn*8 + j];

    float lsum[8], lsq[8];
#pragma unroll
    for (int j = 0; j < 8; ++j) { lsum[j] = 0.f; lsq[j] = 0.f; }

    __syncthreads();

#pragma unroll
    for (int i = 0; i < 8; ++i) {
        float hv[8];
#pragma unroll
        for (int j = 0; j < 8; ++j) {
            hv[j] = acc[i][j] + bb[j];
            lsum[j] += hv[j];
            lsq[j]   = fmaf(hv[j], hv[j], lsq[j]);
        }
        float* hp = h + (size_t)(bm + tm*8 + i) * 256 + (bn + tn*8);
        *(float4*)(hp)     = make_float4(hv[0],hv[1],hv[2],hv[3]);
        *(float4*)(hp + 4) = make_float4(hv[4],hv[5],hv[6],hv[7]);
    }
#pragma unroll
    for (int j = 0; j < 8; ++j) {
        atomicAdd(&csum[tn*8+j], lsum[j]);
        atomicAdd(&csq[tn*8+j],  lsq[j]);
    }
    __syncthreads();
    if (t < 128) {
        atomicAdd(&gsum[bn + t], csum[t]);
        atomicAdd(&gsq[bn + t],  csq[t]);
    }
}

// ---------------------------------------------------------------------------
// Kernel 2: finalize BN stats -> per-channel scale a, shift c
// ---------------------------------------------------------------------------
__global__ void k_stats(const float* __restrict__ gsum, const float* __restrict__ gsq,
                        const float* __restrict__ gamma, const float* __restrict__ beta,
                        float* __restrict__ ab)
{
    int j = threadIdx.x;
    float mean = gsum[j] * INV_B;
    float var  = gsq[j] * INV_B - mean * mean;
    float rstd = rsqrtf(var + 1e-5f);
    float a = gamma[j] * rstd;
    ab[j]       = a;
    ab[256 + j] = beta[j] - mean * a;
}

// ---------------------------------------------------------------------------
// Kernel 3 (rewritten): fused BN+ReLU + capsule projection + routing + softmax.
//
// 256 threads = 4 waves. Lane l = (e = l>>4, o = l&15).
// W_caps split across waves: wave w holds W[e, 64w..64w+63, o] in 64 VGPRs
// (loaded once — no per-batch LDS restaging, no 256-VGPR spill blowup).
// Per 16-row batch:
//   stage:   coop load h rows, BN+ReLU, -> hs[16][256]        (coalesced f4)
//   compute: each wave, per row: partial dot over its 64-d chunk;
//            h read as same-address float4 LDS broadcasts (conflict-free),
//            4 independent FMA chains; partial -> ps[wave][row][lane]
//   reduce:  wave w sums 4 partials for rows 4w..4w+3, then runs the
//            shuffle-based routing + output softmax (verified in R1).
// ---------------------------------------------------------------------------
__global__ __launch_bounds__(256) void k_fuse(
    const float* __restrict__ h, const float* __restrict__ ab,
    const float* __restrict__ wc, const float* __restrict__ ow_g,
    const float* __restrict__ ob_g, float* __restrict__ out)
{
    __shared__ float hs[16][256];     // 16KB: BN'd h rows
    __shared__ float ps[4][16][64];   // 16KB: per-wave partial u

    const int t   = threadIdx.x;
    const int wid = t >> 6;
    const int l   = t & 63;
    const int e   = l >> 4;
    const int o   = l & 15;

    // W chunk into registers: wreg[dd] = wc[e][wid*64+dd][o]
    float wreg[64];
#pragma unroll
    for (int dd = 0; dd < 64; ++dd)
        wreg[dd] = wc[e * 4096 + (wid * 64 + dd) * 16 + o];

    float ow[4];
#pragma unroll
    for (int k = 0; k < 4; ++k) ow[k] = ow_g[k * 16 + o];
    const float ob0 = ob_g[0], ob1 = ob_g[1], ob2 = ob_g[2], ob3 = ob_g[3];

    const float4 a4 = *(const float4*)(ab + l * 4);
    const float4 c4 = *(const float4*)(ab + 256 + l * 4);

    const int rowBase = (int)blockIdx.x * 64;   // 2048 blocks * 64 rows

    for (int batch = 0; batch < 4; ++batch) {
        const int row0 = rowBase + batch * 16;

        __syncthreads();   // prev batch's ps/hs readers done

        // ---- stage 16 rows with BN + ReLU (each thread: 4 rows, 4 cols) ----
#pragma unroll
        for (int p = 0; p < 4; ++p) {
            const int rr = p * 4 + wid;
            float4 hv = *(const float4*)(h + (size_t)(row0 + rr) * 256 + l * 4);
            float4 hn;
            hn.x = fmaxf(fmaf(hv.x, a4.x, c4.x), 0.f);
            hn.y = fmaxf(fmaf(hv.y, a4.y, c4.y), 0.f);
            hn.z = fmaxf(fmaf(hv.z, a4.z, c4.z), 0.f);
            hn.w = fmaxf(fmaf(hv.w, a4.w, c4.w), 0.f);
            *(float4*)&hs[rr][l * 4] = hn;
        }
        __syncthreads();

        // ---- compute: this wave's 64-d partial for all 16 rows ----
#pragma unroll 2
        for (int rr = 0; rr < 16; ++rr) {
            const float* hp = &hs[rr][wid * 64];
            float acc0 = 0.f, acc1 = 0.f, acc2 = 0.f, acc3 = 0.f;
#pragma unroll
            for (int f = 0; f < 4; ++f) {
                float4 q0 = *(const float4*)(hp + 0  + f * 4);
                float4 q1 = *(const float4*)(hp + 16 + f * 4);
                float4 q2 = *(const float4*)(hp + 32 + f * 4);
                float4 q3 = *(const float4*)(hp + 48 + f * 4);
                acc0 = fmaf(q0.x, wreg[ 0 + f*4 + 0], acc0);
                acc0 = fmaf(q0.y, wreg[ 0 + f*4 + 1], acc0);
                acc0 = fmaf(q0.z, wreg[ 0 + f*4 + 2], acc0);
                acc0 = fmaf(q0.w, wreg[ 0 + f*4 + 3], acc0);
                acc1 = fmaf(q1.x, wreg[16 + f*4 + 0], acc1);
                acc1 = fmaf(q1.y, wreg[16 + f*4 + 1], acc1);
                acc1 = fmaf(q1.z, wreg[16 + f*4 + 2], acc1);
                acc1 = fmaf(q1.w, wreg[16 + f*4 + 3], acc1);
                acc2 = fmaf(q2.x, wreg[32 + f*4 + 0], acc2);
                acc2 = fmaf(q2.y, wreg[32 + f*4 + 1], acc2);
                acc2 = fmaf(q2.z, wreg[32 + f*4 + 2], acc2);
                acc2 = fmaf(q2.w, wreg[32 + f*4 + 3], acc2);
                acc3 = fmaf(q3.x, wreg[48 + f*4 + 0], acc3);
                acc3 = fmaf(q3.y, wreg[48 + f*4 + 1], acc3);
                acc3 = fmaf(q3.z, wreg[48 + f*4 + 2], acc3);
                acc3 = fmaf(q3.w, wreg[48 + f*4 + 3], acc3);
            }
            ps[wid][rr][l] = (acc0 + acc1) + (acc2 + acc3);
        }
        __syncthreads();

        // ---- reduce partials + routing for rows 4*wid .. 4*wid+3 ----
#pragma unroll 1
        for (int j = 0; j < 4; ++j) {
            const int rr = wid * 4 + j;
            float uv = (ps[0][rr][l] + ps[1][rr][l]) + (ps[2][rr][l] + ps[3][rr][l]);

            // squash(u)
            float n2 = uv * uv;
            n2 += __shfl_xor(n2, 1); n2 += __shfl_xor(n2, 2);
            n2 += __shfl_xor(n2, 4); n2 += __shfl_xor(n2, 8);
            float nrm = sqrtf(n2);
            float uh  = (nrm / ((1.f + n2) * (nrm + 1e-8f))) * uv;

            float b = 0.f, vv = 0.f;
            for (int it3 = 0; it3 < 3; ++it3) {
                float bmax = b;
                bmax = fmaxf(bmax, __shfl_xor(bmax, 16));
                bmax = fmaxf(bmax, __shfl_xor(bmax, 32));
                float eb = __expf(b - bmax);
                float es = eb;
                es += __shfl_xor(es, 16);
                es += __shfl_xor(es, 32);
                float c = eb / es;
                float sv  = c * uh;
                float sn2 = sv * sv;
                sn2 += __shfl_xor(sn2, 1); sn2 += __shfl_xor(sn2, 2);
                sn2 += __shfl_xor(sn2, 4); sn2 += __shfl_xor(sn2, 8);
                float snrm = sqrtf(sn2);
                vv = (snrm / ((1.f + sn2) * (snrm + 1e-8f))) * sv;
                if (it3 < 2) {
                    float dp = uh * vv;
                    dp += __shfl_xor(dp, 1); dp += __shfl_xor(dp, 2);
                    dp += __shfl_xor(dp, 4); dp += __shfl_xor(dp, 8);
                    b += dp;
                }
            }
            // logits + softmax over k
            float p0 = vv * ow[0], p1 = vv * ow[1], p2 = vv * ow[2], p3 = vv * ow[3];
            p0 += __shfl_xor(p0,1); p0 += __shfl_xor(p0,2); p0 += __shfl_xor(p0,4); p0 += __shfl_xor(p0,8);
            p1 += __shfl_xor(p1,1); p1 += __shfl_xor(p1,2); p1 += __shfl_xor(p1,4); p1 += __shfl_xor(p1,8);
            p2 += __shfl_xor(p2,1); p2 += __shfl_xor(p2,2); p2 += __shfl_xor(p2,4); p2 += __shfl_xor(p2,8);
            p3 += __shfl_xor(p3,1); p3 += __shfl_xor(p3,2); p3 += __shfl_xor(p3,4); p3 += __shfl_xor(p3,8);
            p0 += ob0; p1 += ob1; p2 += ob2; p3 += ob3;
            float mx = fmaxf(fmaxf(p0, p1), fmaxf(p2, p3));
            float e0 = __expf(p0 - mx), e1 = __expf(p1 - mx);
            float e2 = __expf(p2 - mx), e3 = __expf(p3 - mx);
            float inv = 1.f / (e0 + e1 + e2 + e3);
            if (o < 4) {
                float pr = (o == 0) ? e0 : ((o == 1) ? e1 : ((o == 2) ? e2 : e3));
                out[(size_t)(row0 + rr) * 16 + e * 4 + o] = pr * inv;
            }
        }
    }
}

// ---------------------------------------------------------------------------
extern "C" void kernel_launch(void* const* d_in, const int* in_sizes, int n_in,
                              void* d_out, int out_size, void* d_ws, size_t ws_size,
                              hipStream_t stream)
{
    const float* x     = (const float*)d_in[0];
    const float* fc_w  = (const float*)d_in[1];
    const float* fc_b  = (const float*)d_in[2];
    const float* gamma = (const float*)d_in[3];
    const float* beta  = (const float*)d_in[4];
    const float* wc    = (const float*)d_in[5];
    const float* ow    = (const float*)d_in[6];
    const float* ob    = (const float*)d_in[7];
    float* out = (float*)d_out;

    float* gsum = (float*)d_ws;                 // [256]
    float* gsq  = gsum + 256;                   // [256]
    float* ab   = gsum + 512;                   // [512] scale|shift
    float* h    = (float*)((char*)d_ws + 4096); // [131072*256] fp32 = 134MB

    hipMemsetAsync(d_ws, 0, 2048, stream);      // zero gsum/gsq each call

    k_gemm <<<dim3(2048), dim3(256), 0, stream>>>(x, fc_w, fc_b, h, gsum, gsq);
    k_stats<<<dim3(1),    dim3(256), 0, stream>>>(gsum, gsq, gamma, beta, ab);
    k_fuse <<<dim3(2048), dim3(256), 0, stream>>>(h, ab, wc, ow, ob, out);
}

// Round 3
// 349.045 us; speedup vs baseline: 7.3244x; 1.3502x over previous
//
#include <hip/hip_runtime.h>

// GatingNetwork: h = x@fc_w^T + b; BatchNorm(batch axis); ReLU;
// capsule u = h @ W_caps[e]; squash; 3-iter dynamic routing; logits; softmax.
// B=131072, D_IN=HID=256, E=4, CAP=16.

#define BATCH   131072
#define INV_B   (1.0f / 131072.0f)

typedef __attribute__((ext_vector_type(8))) short  short8;   // 8 bf16 (4 VGPR)
typedef __attribute__((ext_vector_type(4))) float  f32x4;

// round-to-nearest-even fp32 -> bf16 (upper 16 bits)
__device__ __forceinline__ unsigned bf16_rn(float f) {
    unsigned u = __float_as_uint(f);
    return (u + 0x7fffu + ((u >> 16) & 1u)) >> 16;
}

// split 8 fp32 into packed bf16 hi + bf16 lo (x ~= hi + lo, err ~2^-18)
__device__ __forceinline__ void split8(const float* v, uint4& hi, uint4& lo) {
    unsigned hb[8], lb[8];
#pragma unroll
    for (int j = 0; j < 8; ++j) {
        unsigned hh = bf16_rn(v[j]);
        float res = v[j] - __uint_as_float(hh << 16);
        hb[j] = hh;
        lb[j] = bf16_rn(res);
    }
    hi = make_uint4(hb[0] | (hb[1] << 16), hb[2] | (hb[3] << 16),
                    hb[4] | (hb[5] << 16), hb[6] | (hb[7] << 16));
    lo = make_uint4(lb[0] | (lb[1] << 16), lb[2] | (lb[3] << 16),
                    lb[4] | (lb[5] << 16), lb[6] | (lb[7] << 16));
}

// ---------------------------------------------------------------------------
// Kernel 1: bf16x3-split MFMA GEMM  h[b,j] = sum_d x[b,d]*w[j,d] + bias[j]
// 128x128 tile, BK=64, 4 waves (2x2), per-wave 64x64 via 4x4 16x16x32 frags.
// acc += Ah*Bh + Ah*Bl + Al*Bh  (fp32 accumulate; Al*Bl dropped, ~2^-18 rel).
// LDS tiles XOR-swizzled in 16B chunks: slot = chunk ^ (row&7)  (T2-style),
// making the stride-128B ds_read_b128 frag loads 2-way (free) instead of
// 16-way conflicted. Per-channel sum/sumsq accumulated for BN.
// ---------------------------------------------------------------------------
__global__ __launch_bounds__(256) void k_gemm(
    const float* __restrict__ x, const float* __restrict__ w,
    const float* __restrict__ bias, float* __restrict__ h,
    float* __restrict__ gsum, float* __restrict__ gsq)
{
    __shared__ ushort Ah[128 * 64];   // 16KB each
    __shared__ ushort Al[128 * 64];
    __shared__ ushort Bh[128 * 64];
    __shared__ ushort Bl[128 * 64];
    __shared__ float  csum[128];
    __shared__ float  csq[128];

    const int t   = threadIdx.x;
    const int wid = t >> 6;
    const int l   = t & 63;
    const int wm  = wid >> 1;          // wave row  (0/1)
    const int wn  = wid & 1;           // wave col  (0/1)
    const int g   = l >> 4;            // k-quarter within frag
    const int lc  = l & 15;            // frag row/col lane

    const int bm = ((int)blockIdx.x >> 1) * 128;
    const int bn = ((int)blockIdx.x & 1) * 128;

    if (t < 128) { csum[t] = 0.f; csq[t] = 0.f; }

    f32x4 acc[4][4];
#pragma unroll
    for (int mi = 0; mi < 4; ++mi)
#pragma unroll
        for (int ni = 0; ni < 4; ++ni)
            acc[mi][ni] = (f32x4){0.f, 0.f, 0.f, 0.f};

    float bb[4];
#pragma unroll
    for (int ni = 0; ni < 4; ++ni)
        bb[ni] = bias[bn + wn * 64 + ni * 16 + lc];

    for (int k0 = 0; k0 < 256; k0 += 64) {
        __syncthreads();   // previous step's frag readers done
        // ---- stage A,B tiles as bf16 hi/lo, swizzled ----
#pragma unroll
        for (int it = 0; it < 4; ++it) {
            const int i    = it * 256 + t;      // 0..1023 chunk id
            const int r    = i >> 3;            // tile row 0..127
            const int c    = i & 7;             // 16B chunk 0..7
            const int slot = c ^ (r & 7);
            const int off  = r * 64 + slot * 8; // ushort units

            const float* ap = x + (size_t)(bm + r) * 256 + k0 + c * 8;
            float4 a0 = *(const float4*)(ap);
            float4 a1 = *(const float4*)(ap + 4);
            float va[8] = {a0.x, a0.y, a0.z, a0.w, a1.x, a1.y, a1.z, a1.w};
            uint4 hi, lo;
            split8(va, hi, lo);
            *(uint4*)&Ah[off] = hi;
            *(uint4*)&Al[off] = lo;

            const float* bp = w + (size_t)(bn + r) * 256 + k0 + c * 8;
            float4 b0 = *(const float4*)(bp);
            float4 b1 = *(const float4*)(bp + 4);
            float vb[8] = {b0.x, b0.y, b0.z, b0.w, b1.x, b1.y, b1.z, b1.w};
            split8(vb, hi, lo);
            *(uint4*)&Bh[off] = hi;
            *(uint4*)&Bl[off] = lo;
        }
        __syncthreads();

        // ---- compute: 2 k-substeps of 32 ----
#pragma unroll
        for (int kk = 0; kk < 2; ++kk) {
            short8 ahf[4], alf[4], bhf[4], blf[4];
#pragma unroll
            for (int mi = 0; mi < 4; ++mi) {
                const int row  = wm * 64 + mi * 16 + lc;
                const int slot = (kk * 4 + g) ^ (row & 7);
                const int off  = row * 64 + slot * 8;
                ahf[mi] = *(const short8*)&Ah[off];
                alf[mi] = *(const short8*)&Al[off];
            }
#pragma unroll
            for (int ni = 0; ni < 4; ++ni) {
                const int row  = wn * 64 + ni * 16 + lc;
                const int slot = (kk * 4 + g) ^ (row & 7);
                const int off  = row * 64 + slot * 8;
                bhf[ni] = *(const short8*)&Bh[off];
                blf[ni] = *(const short8*)&Bl[off];
            }
#pragma unroll
            for (int mi = 0; mi < 4; ++mi)
#pragma unroll
                for (int ni = 0; ni < 4; ++ni) {
                    acc[mi][ni] = __builtin_amdgcn_mfma_f32_16x16x32_bf16(
                        ahf[mi], bhf[ni], acc[mi][ni], 0, 0, 0);
                    acc[mi][ni] = __builtin_amdgcn_mfma_f32_16x16x32_bf16(
                        ahf[mi], blf[ni], acc[mi][ni], 0, 0, 0);
                    acc[mi][ni] = __builtin_amdgcn_mfma_f32_16x16x32_bf16(
                        alf[mi], bhf[ni], acc[mi][ni], 0, 0, 0);
                }
        }
    }

    // ---- epilogue: bias add, store h, per-column stats ----
    float lsum[4] = {0.f, 0.f, 0.f, 0.f};
    float lsq[4]  = {0.f, 0.f, 0.f, 0.f};

#pragma unroll
    for (int mi = 0; mi < 4; ++mi)
#pragma unroll
        for (int ni = 0; ni < 4; ++ni) {
            const int colg = bn + wn * 64 + ni * 16 + lc;
#pragma unroll
            for (int reg = 0; reg < 4; ++reg) {
                const int row = bm + wm * 64 + mi * 16 + g * 4 + reg;
                float hv = acc[mi][ni][reg] + bb[ni];
                h[(size_t)row * 256 + colg] = hv;
                lsum[ni] += hv;
                lsq[ni]   = fmaf(hv, hv, lsq[ni]);
            }
        }

    // reduce over the 4 row-groups (lanes l, l^16, l^32, l^48 share a column)
#pragma unroll
    for (int ni = 0; ni < 4; ++ni) {
        lsum[ni] += __shfl_xor(lsum[ni], 16);
        lsum[ni] += __shfl_xor(lsum[ni], 32);
        lsq[ni]  += __shfl_xor(lsq[ni], 16);
        lsq[ni]  += __shfl_xor(lsq[ni], 32);
    }
    if (l < 16) {
#pragma unroll
        for (int ni = 0; ni < 4; ++ni) {
            atomicAdd(&csum[wn * 64 + ni * 16 + lc], lsum[ni]);
            atomicAdd(&csq[wn * 64 + ni * 16 + lc],  lsq[ni]);
        }
    }
    __syncthreads();
    if (t < 128) {
        atomicAdd(&gsum[bn + t], csum[t]);
        atomicAdd(&gsq[bn + t],  csq[t]);
    }
}

// ---------------------------------------------------------------------------
// Kernel 2: finalize BN stats -> per-channel scale a, shift c
// ---------------------------------------------------------------------------
__global__ void k_stats(const float* __restrict__ gsum, const float* __restrict__ gsq,
                        const float* __restrict__ gamma, const float* __restrict__ beta,
                        float* __restrict__ ab)
{
    int j = threadIdx.x;
    float mean = gsum[j] * INV_B;
    float var  = gsq[j] * INV_B - mean * mean;
    float rstd = rsqrtf(var + 1e-5f);
    float a = gamma[j] * rstd;
    ab[j]       = a;
    ab[256 + j] = beta[j] - mean * a;
}

// ---------------------------------------------------------------------------
// Kernel 3: fused BN+ReLU + capsule projection + routing + softmax.
// (unchanged from R2 — verified; ~207us, DS-pipe bound; R4 target)
// ---------------------------------------------------------------------------
__global__ __launch_bounds__(256) void k_fuse(
    const float* __restrict__ h, const float* __restrict__ ab,
    const float* __restrict__ wc, const float* __restrict__ ow_g,
    const float* __restrict__ ob_g, float* __restrict__ out)
{
    __shared__ float hs[16][256];     // 16KB: BN'd h rows
    __shared__ float ps[4][16][64];   // 16KB: per-wave partial u

    const int t   = threadIdx.x;
    const int wid = t >> 6;
    const int l   = t & 63;
    const int e   = l >> 4;
    const int o   = l & 15;

    float wreg[64];
#pragma unroll
    for (int dd = 0; dd < 64; ++dd)
        wreg[dd] = wc[e * 4096 + (wid * 64 + dd) * 16 + o];

    float ow[4];
#pragma unroll
    for (int k = 0; k < 4; ++k) ow[k] = ow_g[k * 16 + o];
    const float ob0 = ob_g[0], ob1 = ob_g[1], ob2 = ob_g[2], ob3 = ob_g[3];

    const float4 a4 = *(const float4*)(ab + l * 4);
    const float4 c4 = *(const float4*)(ab + 256 + l * 4);

    const int rowBase = (int)blockIdx.x * 64;   // 2048 blocks * 64 rows

    for (int batch = 0; batch < 4; ++batch) {
        const int row0 = rowBase + batch * 16;

        __syncthreads();

#pragma unroll
        for (int p = 0; p < 4; ++p) {
            const int rr = p * 4 + wid;
            float4 hv = *(const float4*)(h + (size_t)(row0 + rr) * 256 + l * 4);
            float4 hn;
            hn.x = fmaxf(fmaf(hv.x, a4.x, c4.x), 0.f);
            hn.y = fmaxf(fmaf(hv.y, a4.y, c4.y), 0.f);
            hn.z = fmaxf(fmaf(hv.z, a4.z, c4.z), 0.f);
            hn.w = fmaxf(fmaf(hv.w, a4.w, c4.w), 0.f);
            *(float4*)&hs[rr][l * 4] = hn;
        }
        __syncthreads();

#pragma unroll 2
        for (int rr = 0; rr < 16; ++rr) {
            const float* hp = &hs[rr][wid * 64];
            float acc0 = 0.f, acc1 = 0.f, acc2 = 0.f, acc3 = 0.f;
#pragma unroll
            for (int f = 0; f < 4; ++f) {
                float4 q0 = *(const float4*)(hp + 0  + f * 4);
                float4 q1 = *(const float4*)(hp + 16 + f * 4);
                float4 q2 = *(const float4*)(hp + 32 + f * 4);
                float4 q3 = *(const float4*)(hp + 48 + f * 4);
                acc0 = fmaf(q0.x, wreg[ 0 + f*4 + 0], acc0);
                acc0 = fmaf(q0.y, wreg[ 0 + f*4 + 1], acc0);
                acc0 = fmaf(q0.z, wreg[ 0 + f*4 + 2], acc0);
                acc0 = fmaf(q0.w, wreg[ 0 + f*4 + 3], acc0);
                acc1 = fmaf(q1.x, wreg[16 + f*4 + 0], acc1);
                acc1 = fmaf(q1.y, wreg[16 + f*4 + 1], acc1);
                acc1 = fmaf(q1.z, wreg[16 + f*4 + 2], acc1);
                acc1 = fmaf(q1.w, wreg[16 + f*4 + 3], acc1);
                acc2 = fmaf(q2.x, wreg[32 + f*4 + 0], acc2);
                acc2 = fmaf(q2.y, wreg[32 + f*4 + 1], acc2);
                acc2 = fmaf(q2.z, wreg[32 + f*4 + 2], acc2);
                acc2 = fmaf(q2.w, wreg[32 + f*4 + 3], acc2);
                acc3 = fmaf(q3.x, wreg[48 + f*4 + 0], acc3);
                acc3 = fmaf(q3.y, wreg[48 + f*4 + 1], acc3);
                acc3 = fmaf(q3.z, wreg[48 + f*4 + 2], acc3);
                acc3 = fmaf(q3.w, wreg[48 + f*4 + 3], acc3);
            }
            ps[wid][rr][l] = (acc0 + acc1) + (acc2 + acc3);
        }
        __syncthreads();

#pragma unroll 1
        for (int j = 0; j < 4; ++j) {
            const int rr = wid * 4 + j;
            float uv = (ps[0][rr][l] + ps[1][rr][l]) + (ps[2][rr][l] + ps[3][rr][l]);

            float n2 = uv * uv;
            n2 += __shfl_xor(n2, 1); n2 += __shfl_xor(n2, 2);
            n2 += __shfl_xor(n2, 4); n2 += __shfl_xor(n2, 8);
            float nrm = sqrtf(n2);
            float uh  = (nrm / ((1.f + n2) * (nrm + 1e-8f))) * uv;

            float b = 0.f, vv = 0.f;
            for (int it3 = 0; it3 < 3; ++it3) {
                float bmax = b;
                bmax = fmaxf(bmax, __shfl_xor(bmax, 16));
                bmax = fmaxf(bmax, __shfl_xor(bmax, 32));
                float eb = __expf(b - bmax);
                float es = eb;
                es += __shfl_xor(es, 16);
                es += __shfl_xor(es, 32);
                float c = eb / es;
                float sv  = c * uh;
                float sn2 = sv * sv;
                sn2 += __shfl_xor(sn2, 1); sn2 += __shfl_xor(sn2, 2);
                sn2 += __shfl_xor(sn2, 4); sn2 += __shfl_xor(sn2, 8);
                float snrm = sqrtf(sn2);
                vv = (snrm / ((1.f + sn2) * (snrm + 1e-8f))) * sv;
                if (it3 < 2) {
                    float dp = uh * vv;
                    dp += __shfl_xor(dp, 1); dp += __shfl_xor(dp, 2);
                    dp += __shfl_xor(dp, 4); dp += __shfl_xor(dp, 8);
                    b += dp;
                }
            }
            float p0 = vv * ow[0], p1 = vv * ow[1], p2 = vv * ow[2], p3 = vv * ow[3];
            p0 += __shfl_xor(p0,1); p0 += __shfl_xor(p0,2); p0 += __shfl_xor(p0,4); p0 += __shfl_xor(p0,8);
            p1 += __shfl_xor(p1,1); p1 += __shfl_xor(p1,2); p1 += __shfl_xor(p1,4); p1 += __shfl_xor(p1,8);
            p2 += __shfl_xor(p2,1); p2 += __shfl_xor(p2,2); p2 += __shfl_xor(p2,4); p2 += __shfl_xor(p2,8);
            p3 += __shfl_xor(p3,1); p3 += __shfl_xor(p3,2); p3 += __shfl_xor(p3,4); p3 += __shfl_xor(p3,8);
            p0 += ob0; p1 += ob1; p2 += ob2; p3 += ob3;
            float mx = fmaxf(fmaxf(p0, p1), fmaxf(p2, p3));
            float e0 = __expf(p0 - mx), e1 = __expf(p1 - mx);
            float e2 = __expf(p2 - mx), e3 = __expf(p3 - mx);
            float inv = 1.f / (e0 + e1 + e2 + e3);
            if (o < 4) {
                float pr = (o == 0) ? e0 : ((o == 1) ? e1 : ((o == 2) ? e2 : e3));
                out[(size_t)(row0 + rr) * 16 + e * 4 + o] = pr * inv;
            }
        }
    }
}

// ---------------------------------------------------------------------------
extern "C" void kernel_launch(void* const* d_in, const int* in_sizes, int n_in,
                              void* d_out, int out_size, void* d_ws, size_t ws_size,
                              hipStream_t stream)
{
    const float* x     = (const float*)d_in[0];
    const float* fc_w  = (const float*)d_in[1];
    const float* fc_b  = (const float*)d_in[2];
    const float* gamma = (const float*)d_in[3];
    const float* beta  = (const float*)d_in[4];
    const float* wc    = (const float*)d_in[5];
    const float* ow    = (const float*)d_in[6];
    const float* ob    = (const float*)d_in[7];
    float* out = (float*)d_out;

    float* gsum = (float*)d_ws;                 // [256]
    float* gsq  = gsum + 256;                   // [256]
    float* ab   = gsum + 512;                   // [512] scale|shift
    float* h    = (float*)((char*)d_ws + 4096); // [131072*256] fp32 = 134MB

    hipMemsetAsync(d_ws, 0, 2048, stream);      // zero gsum/gsq each call

    k_gemm <<<dim3(2048), dim3(256), 0, stream>>>(x, fc_w, fc_b, h, gsum, gsq);
    k_stats<<<dim3(1),    dim3(256), 0, stream>>>(gsum, gsq, gamma, beta, ab);
    k_fuse <<<dim3(2048), dim3(256), 0, stream>>>(h, ab, wc, ow, ob, out);
}

// Round 4
// 156.589 us; speedup vs baseline: 16.3266x; 2.2291x over previous
//
#include <hip/hip_runtime.h>

// GatingNetwork: h = x@fc_w^T + b; BatchNorm(batch axis); ReLU;
// capsule u = h @ W_caps[e]; squash; 3-iter dynamic routing; logits; softmax.
// B=131072, D_IN=HID=256, E=4, CAP=16.
//
// N_IN_CAPS==1 collinearity: s = c*u_hat, so squash(s) and u_hat·v reduce to
// scalar recurrences on (c, |u_hat|); logits = (alpha*c*sc) * (u·ow_k).

#define BATCH   131072
#define INV_B   (1.0f / 131072.0f)

typedef __attribute__((ext_vector_type(8))) short  short8;   // 8 bf16 (4 VGPR)
typedef __attribute__((ext_vector_type(4))) float  f32x4;

// round-to-nearest-even fp32 -> bf16 (upper 16 bits)
__device__ __forceinline__ unsigned bf16_rn(float f) {
    unsigned u = __float_as_uint(f);
    return (u + 0x7fffu + ((u >> 16) & 1u)) >> 16;
}

// split 8 fp32 into packed bf16 hi + bf16 lo (x ~= hi + lo, err ~2^-18)
__device__ __forceinline__ void split8(const float* v, uint4& hi, uint4& lo) {
    unsigned hb[8], lb[8];
#pragma unroll
    for (int j = 0; j < 8; ++j) {
        unsigned hh = bf16_rn(v[j]);
        float res = v[j] - __uint_as_float(hh << 16);
        hb[j] = hh;
        lb[j] = bf16_rn(res);
    }
    hi = make_uint4(hb[0] | (hb[1] << 16), hb[2] | (hb[3] << 16),
                    hb[4] | (hb[5] << 16), hb[6] | (hb[7] << 16));
    lo = make_uint4(lb[0] | (lb[1] << 16), lb[2] | (lb[3] << 16),
                    lb[4] | (lb[5] << 16), lb[6] | (lb[7] << 16));
}

// ---------------------------------------------------------------------------
// Kernel 1: bf16x3-split MFMA GEMM  h[b,j] = sum_d x[b,d]*w[j,d] + bias[j]
// (unchanged from R3 — ~85us measured)
// ---------------------------------------------------------------------------
__global__ __launch_bounds__(256) void k_gemm(
    const float* __restrict__ x, const float* __restrict__ w,
    const float* __restrict__ bias, float* __restrict__ h,
    float* __restrict__ gsum, float* __restrict__ gsq)
{
    __shared__ ushort Ah[128 * 64];   // 16KB each
    __shared__ ushort Al[128 * 64];
    __shared__ ushort Bh[128 * 64];
    __shared__ ushort Bl[128 * 64];
    __shared__ float  csum[128];
    __shared__ float  csq[128];

    const int t   = threadIdx.x;
    const int wid = t >> 6;
    const int l   = t & 63;
    const int wm  = wid >> 1;          // wave row  (0/1)
    const int wn  = wid & 1;           // wave col  (0/1)
    const int g   = l >> 4;            // k-quarter within frag
    const int lc  = l & 15;            // frag row/col lane

    const int bm = ((int)blockIdx.x >> 1) * 128;
    const int bn = ((int)blockIdx.x & 1) * 128;

    if (t < 128) { csum[t] = 0.f; csq[t] = 0.f; }

    f32x4 acc[4][4];
#pragma unroll
    for (int mi = 0; mi < 4; ++mi)
#pragma unroll
        for (int ni = 0; ni < 4; ++ni)
            acc[mi][ni] = (f32x4){0.f, 0.f, 0.f, 0.f};

    float bb[4];
#pragma unroll
    for (int ni = 0; ni < 4; ++ni)
        bb[ni] = bias[bn + wn * 64 + ni * 16 + lc];

    for (int k0 = 0; k0 < 256; k0 += 64) {
        __syncthreads();   // previous step's frag readers done
#pragma unroll
        for (int it = 0; it < 4; ++it) {
            const int i    = it * 256 + t;      // 0..1023 chunk id
            const int r    = i >> 3;            // tile row 0..127
            const int c    = i & 7;             // 16B chunk 0..7
            const int slot = c ^ (r & 7);
            const int off  = r * 64 + slot * 8; // ushort units

            const float* ap = x + (size_t)(bm + r) * 256 + k0 + c * 8;
            float4 a0 = *(const float4*)(ap);
            float4 a1 = *(const float4*)(ap + 4);
            float va[8] = {a0.x, a0.y, a0.z, a0.w, a1.x, a1.y, a1.z, a1.w};
            uint4 hi, lo;
            split8(va, hi, lo);
            *(uint4*)&Ah[off] = hi;
            *(uint4*)&Al[off] = lo;

            const float* bp = w + (size_t)(bn + r) * 256 + k0 + c * 8;
            float4 b0 = *(const float4*)(bp);
            float4 b1 = *(const float4*)(bp + 4);
            float vb[8] = {b0.x, b0.y, b0.z, b0.w, b1.x, b1.y, b1.z, b1.w};
            split8(vb, hi, lo);
            *(uint4*)&Bh[off] = hi;
            *(uint4*)&Bl[off] = lo;
        }
        __syncthreads();

#pragma unroll
        for (int kk = 0; kk < 2; ++kk) {
            short8 ahf[4], alf[4], bhf[4], blf[4];
#pragma unroll
            for (int mi = 0; mi < 4; ++mi) {
                const int row  = wm * 64 + mi * 16 + lc;
                const int slot = (kk * 4 + g) ^ (row & 7);
                const int off  = row * 64 + slot * 8;
                ahf[mi] = *(const short8*)&Ah[off];
                alf[mi] = *(const short8*)&Al[off];
            }
#pragma unroll
            for (int ni = 0; ni < 4; ++ni) {
                const int row  = wn * 64 + ni * 16 + lc;
                const int slot = (kk * 4 + g) ^ (row & 7);
                const int off  = row * 64 + slot * 8;
                bhf[ni] = *(const short8*)&Bh[off];
                blf[ni] = *(const short8*)&Bl[off];
            }
#pragma unroll
            for (int mi = 0; mi < 4; ++mi)
#pragma unroll
                for (int ni = 0; ni < 4; ++ni) {
                    acc[mi][ni] = __builtin_amdgcn_mfma_f32_16x16x32_bf16(
                        ahf[mi], bhf[ni], acc[mi][ni], 0, 0, 0);
                    acc[mi][ni] = __builtin_amdgcn_mfma_f32_16x16x32_bf16(
                        ahf[mi], blf[ni], acc[mi][ni], 0, 0, 0);
                    acc[mi][ni] = __builtin_amdgcn_mfma_f32_16x16x32_bf16(
                        alf[mi], bhf[ni], acc[mi][ni], 0, 0, 0);
                }
        }
    }

    float lsum[4] = {0.f, 0.f, 0.f, 0.f};
    float lsq[4]  = {0.f, 0.f, 0.f, 0.f};

#pragma unroll
    for (int mi = 0; mi < 4; ++mi)
#pragma unroll
        for (int ni = 0; ni < 4; ++ni) {
            const int colg = bn + wn * 64 + ni * 16 + lc;
#pragma unroll
            for (int reg = 0; reg < 4; ++reg) {
                const int row = bm + wm * 64 + mi * 16 + g * 4 + reg;
                float hv = acc[mi][ni][reg] + bb[ni];
                h[(size_t)row * 256 + colg] = hv;
                lsum[ni] += hv;
                lsq[ni]   = fmaf(hv, hv, lsq[ni]);
            }
        }

#pragma unroll
    for (int ni = 0; ni < 4; ++ni) {
        lsum[ni] += __shfl_xor(lsum[ni], 16);
        lsum[ni] += __shfl_xor(lsum[ni], 32);
        lsq[ni]  += __shfl_xor(lsq[ni], 16);
        lsq[ni]  += __shfl_xor(lsq[ni], 32);
    }
    if (l < 16) {
#pragma unroll
        for (int ni = 0; ni < 4; ++ni) {
            atomicAdd(&csum[wn * 64 + ni * 16 + lc], lsum[ni]);
            atomicAdd(&csq[wn * 64 + ni * 16 + lc],  lsq[ni]);
        }
    }
    __syncthreads();
    if (t < 128) {
        atomicAdd(&gsum[bn + t], csum[t]);
        atomicAdd(&gsq[bn + t],  csq[t]);
    }
}

// ---------------------------------------------------------------------------
// Kernel 2: finalize BN stats -> per-channel scale a, shift c
// ---------------------------------------------------------------------------
__global__ void k_stats(const float* __restrict__ gsum, const float* __restrict__ gsq,
                        const float* __restrict__ gamma, const float* __restrict__ beta,
                        float* __restrict__ ab)
{
    int j = threadIdx.x;
    float mean = gsum[j] * INV_B;
    float var  = gsq[j] * INV_B - mean * mean;
    float rstd = rsqrtf(var + 1e-5f);
    float a = gamma[j] * rstd;
    ab[j]       = a;
    ab[256 + j] = beta[j] - mean * a;
}

// ---------------------------------------------------------------------------
// Kernel 3 (rewritten): BN+ReLU + MFMA capsule projection + scalar routing.
//
// Block = 256 thr = 4 waves, 64 rows. Two 32-row sub-batches:
//   stage:  h rows -> BN+ReLU -> bf16 hi/lo -> Hh/Hl[32][256], XOR-swizzled
//   mfma:   wave w computes u[rows][c = w*16..w*16+15]:
//           C = (Wc^T slice, reg-resident hi/lo frags) x (hn^T from LDS),
//           bf16x3 split, 24 MFMA + 32 ds_read_b128 per wave per sub-batch
//   u -> us[64][68] f32 (padded pitch)
// Routing pass: lane = (row = l&15 within wave's 16, e = l>>4); u row-chunk
// in-lane; collinearity reduction => scalar iterations; shfl_xor 16/32 for
// the expert softmax; logits via t_k = u·ow_k (ows LDS broadcast).
// ---------------------------------------------------------------------------
__global__ __launch_bounds__(256) void k_fuse(
    const float* __restrict__ h, const float* __restrict__ ab,
    const float* __restrict__ wc, const float* __restrict__ ow_g,
    const float* __restrict__ ob_g, float* __restrict__ out)
{
    __shared__ ushort Hh[32 * 256];   // 16KB
    __shared__ ushort Hl[32 * 256];   // 16KB
    __shared__ float  us[64 * 68];    // 17KB
    __shared__ float  ows[64];

    const int t   = threadIdx.x;
    const int wid = t >> 6;
    const int l   = t & 63;
    const int g   = l >> 4;           // 0..3
    const int lc  = l & 15;

    if (t < 64) ows[t] = ow_g[t];

    // ---- preload A-frags: A[i][k] = Wc[e=wid][d=k][o=i], i=lc, frag k-chunk ----
    short8 afh[8], afl[8];
#pragma unroll
    for (int ks = 0; ks < 8; ++ks) {
        union { ushort u16[8]; short8 v; } ph, pl;
#pragma unroll
        for (int j = 0; j < 8; ++j) {
            const int d = ks * 32 + g * 8 + j;
            float wv = wc[wid * 4096 + d * 16 + lc];
            unsigned hh = bf16_rn(wv);
            float res = wv - __uint_as_float(hh << 16);
            ph.u16[j] = (ushort)hh;
            pl.u16[j] = (ushort)bf16_rn(res);
        }
        afh[ks] = ph.v;
        afl[ks] = pl.v;
    }

    // ---- BN coefficients for this thread's 8 staging columns ----
    const int c8 = (t & 31) * 8;      // column group
    float a_[8], cj[8];
    {
        float4 x0 = *(const float4*)(ab + c8);
        float4 x1 = *(const float4*)(ab + c8 + 4);
        float4 y0 = *(const float4*)(ab + 256 + c8);
        float4 y1 = *(const float4*)(ab + 256 + c8 + 4);
        a_[0]=x0.x; a_[1]=x0.y; a_[2]=x0.z; a_[3]=x0.w;
        a_[4]=x1.x; a_[5]=x1.y; a_[6]=x1.z; a_[7]=x1.w;
        cj[0]=y0.x; cj[1]=y0.y; cj[2]=y0.z; cj[3]=y0.w;
        cj[4]=y1.x; cj[5]=y1.y; cj[6]=y1.z; cj[7]=y1.w;
    }

    const int rowBase = (int)blockIdx.x * 64;

#pragma unroll
    for (int sub = 0; sub < 2; ++sub) {
        const int row0 = rowBase + sub * 32;

        __syncthreads();   // Hh/Hl readers of previous sub done

        // ---- stage 32 rows: BN + ReLU + bf16 split, swizzled ----
#pragma unroll
        for (int it = 0; it < 4; ++it) {
            const int r = it * 8 + (t >> 5);          // 0..31
            const float* hp = h + (size_t)(row0 + r) * 256 + c8;
            float4 v0 = *(const float4*)(hp);
            float4 v1 = *(const float4*)(hp + 4);
            float hv[8] = {v0.x, v0.y, v0.z, v0.w, v1.x, v1.y, v1.z, v1.w};
#pragma unroll
            for (int j = 0; j < 8; ++j)
                hv[j] = fmaxf(fmaf(hv[j], a_[j], cj[j]), 0.f);
            uint4 hi, lo;
            split8(hv, hi, lo);
            const int slot = (t & 31) ^ (r & 7);
            *(uint4*)&Hh[r * 256 + slot * 8] = hi;
            *(uint4*)&Hl[r * 256 + slot * 8] = lo;
        }
        __syncthreads();

        // ---- MFMA: u[nt*16+n][wid*16+i] for 32 rows ----
        f32x4 acc0 = (f32x4){0.f,0.f,0.f,0.f};
        f32x4 acc1 = (f32x4){0.f,0.f,0.f,0.f};
#pragma unroll
        for (int ks = 0; ks < 8; ++ks) {
            {
                const int row  = lc;                   // nt = 0
                const int slot = (ks * 4 + g) ^ (row & 7);
                short8 bh = *(const short8*)&Hh[row * 256 + slot * 8];
                short8 bl = *(const short8*)&Hl[row * 256 + slot * 8];
                acc0 = __builtin_amdgcn_mfma_f32_16x16x32_bf16(afh[ks], bh, acc0, 0,0,0);
                acc0 = __builtin_amdgcn_mfma_f32_16x16x32_bf16(afh[ks], bl, acc0, 0,0,0);
                acc0 = __builtin_amdgcn_mfma_f32_16x16x32_bf16(afl[ks], bh, acc0, 0,0,0);
            }
            {
                const int row  = 16 + lc;              // nt = 1
                const int slot = (ks * 4 + g) ^ (row & 7);
                short8 bh = *(const short8*)&Hh[row * 256 + slot * 8];
                short8 bl = *(const short8*)&Hl[row * 256 + slot * 8];
                acc1 = __builtin_amdgcn_mfma_f32_16x16x32_bf16(afh[ks], bh, acc1, 0,0,0);
                acc1 = __builtin_amdgcn_mfma_f32_16x16x32_bf16(afh[ks], bl, acc1, 0,0,0);
                acc1 = __builtin_amdgcn_mfma_f32_16x16x32_bf16(afl[ks], bh, acc1, 0,0,0);
            }
        }
        // C layout: lane holds u[row = nt*16+lc][c = wid*16 + g*4 + reg]
        {
            const int r0 = sub * 32 + lc;
            *(float4*)&us[r0 * 68 + wid * 16 + g * 4] =
                make_float4(acc0[0], acc0[1], acc0[2], acc0[3]);
            *(float4*)&us[(r0 + 16) * 68 + wid * 16 + g * 4] =
                make_float4(acc1[0], acc1[1], acc1[2], acc1[3]);
        }
    }
    __syncthreads();

    // ---- routing: lane = (row_l = wid*16 + lc, e = g) ----
    const int row_l = wid * 16 + lc;
    float u[16];
#pragma unroll
    for (int q = 0; q < 4; ++q) {
        float4 v4 = *(const float4*)&us[row_l * 68 + g * 16 + q * 4];
        u[q*4+0] = v4.x; u[q*4+1] = v4.y; u[q*4+2] = v4.z; u[q*4+3] = v4.w;
    }

    float n2 = 0.f;
#pragma unroll
    for (int o = 0; o < 16; ++o) n2 = fmaf(u[o], u[o], n2);
    const float nrm = sqrtf(n2);
    const float sc  = nrm / ((1.f + n2) * (nrm + 1e-8f));  // u_hat = sc*u
    const float nh2 = sc * sc * n2;                         // |u_hat|^2
    const float nh  = sc * nrm;                             // |u_hat|

    // t_k = u . ow[k]  via LDS broadcast
    float tk[4];
#pragma unroll
    for (int k = 0; k < 4; ++k) {
        float s = 0.f;
#pragma unroll
        for (int q = 0; q < 4; ++q) {
            float4 w4 = *(const float4*)&ows[k * 16 + q * 4];
            s = fmaf(u[q*4+0], w4.x, s);
            s = fmaf(u[q*4+1], w4.y, s);
            s = fmaf(u[q*4+2], w4.z, s);
            s = fmaf(u[q*4+3], w4.w, s);
        }
        tk[k] = s;
    }

    // 3 routing iterations, scalar (collinearity: s = c*u_hat)
    float b = 0.f, alc = 0.f;
#pragma unroll
    for (int it3 = 0; it3 < 3; ++it3) {
        float bmax = fmaxf(b, __shfl_xor(b, 16));
        bmax = fmaxf(bmax, __shfl_xor(bmax, 32));
        float eb = __expf(b - bmax);
        float es = eb + __shfl_xor(eb, 16);
        es += __shfl_xor(es, 32);
        float c = eb / es;
        float ns  = c * nh;            // |s|
        float ns2 = c * c * nh2;       // |s|^2
        float av  = ns / ((1.f + ns2) * (ns + 1e-8f));   // v = av*c*u_hat
        alc = av * c;
        if (it3 < 2) b += alc * nh2;   // u_hat . v
    }

    // logits_k = (alc*sc) * t_k + ob_k ; softmax over k; write f4
    const float vs = alc * sc;
    float p0 = fmaf(vs, tk[0], ob_g[0]);
    float p1 = fmaf(vs, tk[1], ob_g[1]);
    float p2 = fmaf(vs, tk[2], ob_g[2]);
    float p3 = fmaf(vs, tk[3], ob_g[3]);
    float mx = fmaxf(fmaxf(p0, p1), fmaxf(p2, p3));
    float e0 = __expf(p0 - mx), e1 = __expf(p1 - mx);
    float e2 = __expf(p2 - mx), e3 = __expf(p3 - mx);
    float inv = 1.f / (e0 + e1 + e2 + e3);
    *(float4*)&out[(size_t)(rowBase + row_l) * 16 + g * 4] =
        make_float4(e0 * inv, e1 * inv, e2 * inv, e3 * inv);
}

// ---------------------------------------------------------------------------
extern "C" void kernel_launch(void* const* d_in, const int* in_sizes, int n_in,
                              void* d_out, int out_size, void* d_ws, size_t ws_size,
                              hipStream_t stream)
{
    const float* x     = (const float*)d_in[0];
    const float* fc_w  = (const float*)d_in[1];
    const float* fc_b  = (const float*)d_in[2];
    const float* gamma = (const float*)d_in[3];
    const float* beta  = (const float*)d_in[4];
    const float* wc    = (const float*)d_in[5];
    const float* ow    = (const float*)d_in[6];
    const float* ob    = (const float*)d_in[7];
    float* out = (float*)d_out;

    float* gsum = (float*)d_ws;                 // [256]
    float* gsq  = gsum + 256;                   // [256]
    float* ab   = gsum + 512;                   // [512] scale|shift
    float* h    = (float*)((char*)d_ws + 4096); // [131072*256] fp32 = 134MB

    hipMemsetAsync(d_ws, 0, 2048, stream);      // zero gsum/gsq each call

    k_gemm <<<dim3(2048), dim3(256), 0, stream>>>(x, fc_w, fc_b, h, gsum, gsq);
    k_stats<<<dim3(1),    dim3(256), 0, stream>>>(gsum, gsq, gamma, beta, ab);
    k_fuse <<<dim3(2048), dim3(256), 0, stream>>>(h, ab, wc, ow, ob, out);
}

// Round 5
// 131.895 us; speedup vs baseline: 19.3834x; 1.1872x over previous
//
#include <hip/hip_runtime.h>
#include <hip/hip_bf16.h>

// GatingNetwork: h = x@fc_w^T + b; BatchNorm(batch axis); ReLU;
// capsule u = h @ W_caps[e]; squash; 3-iter dynamic routing; logits; softmax.
// B=131072, D_IN=HID=256, E=4, CAP=16.
//
// Pipeline: k_prep (split+swizzle fc_w -> d_out scratch) ; k_gemm (bf16x3
// MFMA, BM=128 x BN=256, B staged via global_load_lds from pre-swizzled
// planes, BN stats epilogue) ; k_stats ; k_fuse (MFMA capsules + collinear
// scalar routing — verified R4, ~5us warm).

#define BATCH   131072
#define INV_B   (1.0f / 131072.0f)

typedef __attribute__((ext_vector_type(8))) short  short8;   // 8 bf16 (4 VGPR)
typedef __attribute__((ext_vector_type(4))) float  f32x4;

// round-to-nearest-even fp32 -> bf16 (integer path; used where cost is moot)
__device__ __forceinline__ unsigned bf16_rn(float f) {
    unsigned u = __float_as_uint(f);
    return (u + 0x7fffu + ((u >> 16) & 1u)) >> 16;
}

// split 8 fp32 into packed bf16 hi + bf16 lo (v ~= hi + lo).
// Uses compiler bf16 casts (packs to v_cvt_pk_bf16_f32); residual carried in
// lo, so exact hi rounding mode is uncritical for the 3-product scheme.
__device__ __forceinline__ void split8(const float* v, uint4& hi, uint4& lo) {
    unsigned hb[8], lb[8];
#pragma unroll
    for (int j = 0; j < 8; ++j) {
        union { __hip_bfloat16 b; ushort u; } ch, cl;
        ch.b = __float2bfloat16(v[j]);
        float res = v[j] - __bfloat162float(ch.b);
        cl.b = __float2bfloat16(res);
        hb[j] = ch.u;
        lb[j] = cl.u;
    }
    hi = make_uint4(hb[0] | (hb[1] << 16), hb[2] | (hb[3] << 16),
                    hb[4] | (hb[5] << 16), hb[6] | (hb[7] << 16));
    lo = make_uint4(lb[0] | (lb[1] << 16), lb[2] | (lb[3] << 16),
                    lb[4] | (lb[5] << 16), lb[6] | (lb[7] << 16));
}

// ---------------------------------------------------------------------------
// Kernel 0: pre-split fc_w into bf16 hi/lo planes, pre-XOR-swizzled so that a
// LINEAR copy into LDS (global_load_lds) yields the swizzled B tile.
// Layout (ushort units): hi plane ks at wsp[ks*16384 + r*64 + slot*8 + j],
// lo planes at +65536. slot = c ^ (r&7), chunk c = 8 k's.
// ---------------------------------------------------------------------------
__global__ void k_prep(const float* __restrict__ w, ushort* __restrict__ wsp)
{
    const int cid = (int)blockIdx.x * 256 + threadIdx.x;  // 0..8191
    const int ks = cid >> 11;
    const int r  = (cid >> 3) & 255;
    const int c  = cid & 7;
    const float* wp = w + r * 256 + ks * 64 + c * 8;
    float4 v0 = *(const float4*)(wp);
    float4 v1 = *(const float4*)(wp + 4);
    float va[8] = {v0.x, v0.y, v0.z, v0.w, v1.x, v1.y, v1.z, v1.w};
    uint4 hi, lo;
    split8(va, hi, lo);
    const int slot = c ^ (r & 7);
    *(uint4*)&wsp[ks * 16384 + r * 64 + slot * 8]         = hi;
    *(uint4*)&wsp[65536 + ks * 16384 + r * 64 + slot * 8] = lo;
}

// ---------------------------------------------------------------------------
// Kernel 1: bf16x3-split MFMA GEMM  h[b,j] = sum_d x[b,d]*w[j,d] + bias[j]
// BM=128, BN=256 (full), BK=64, 512 thr = 8 waves (2M x 4N), 64x64 per wave.
// A (x): global->reg->split->swizzled ds_write (x read ONCE per row).
// B (w): global_load_lds dwordx4 from pre-swizzled planes (zero VALU).
// acc += Ah*Bh + Ah*Bl + Al*Bh. Per-channel sum/sumsq epilogue for BN.
// ---------------------------------------------------------------------------
__global__ __launch_bounds__(512) void k_gemm(
    const float* __restrict__ x, const ushort* __restrict__ wsp,
    const float* __restrict__ bias, float* __restrict__ h,
    float* __restrict__ gsum, float* __restrict__ gsq)
{
    __shared__ ushort Ah[128 * 64];   // 16KB
    __shared__ ushort Al[128 * 64];   // 16KB
    __shared__ ushort Bh[256 * 64];   // 32KB
    __shared__ ushort Bl[256 * 64];   // 32KB
    __shared__ float  csum[256];
    __shared__ float  csq[256];

    const int t   = threadIdx.x;
    const int wid = t >> 6;            // 0..7
    const int l   = t & 63;
    const int wm  = wid >> 2;          // 0..1  (64-row slab)
    const int wn  = wid & 3;           // 0..3  (64-col slab)
    const int g   = l >> 4;
    const int lc  = l & 15;
    const int bm  = (int)blockIdx.x * 128;

    if (t < 256) { csum[t] = 0.f; csq[t] = 0.f; }

    f32x4 acc[4][4];
#pragma unroll
    for (int mi = 0; mi < 4; ++mi)
#pragma unroll
        for (int ni = 0; ni < 4; ++ni)
            acc[mi][ni] = (f32x4){0.f, 0.f, 0.f, 0.f};

    float bb[4];
#pragma unroll
    for (int ni = 0; ni < 4; ++ni)
        bb[ni] = bias[wn * 64 + ni * 16 + lc];

    for (int ks = 0; ks < 4; ++ks) {
        const int k0 = ks * 64;
        __syncthreads();   // previous step's tile readers done

        // ---- B: async DMA of pre-swizzled planes (1KB per wave per instr) ----
        {
            const char* srch = (const char*)(wsp + ks * 16384);
            const char* srcl = (const char*)(wsp + 65536 + ks * 16384);
#pragma unroll
            for (int i = 0; i < 4; ++i) {
                const int off = wid * 4096 + i * 1024;   // bytes, wave-uniform
                __builtin_amdgcn_global_load_lds(
                    (const __attribute__((address_space(1))) unsigned*)(srch + off + l * 16),
                    (__attribute__((address_space(3))) unsigned*)((char*)Bh + off),
                    16, 0, 0);
                __builtin_amdgcn_global_load_lds(
                    (const __attribute__((address_space(1))) unsigned*)(srcl + off + l * 16),
                    (__attribute__((address_space(3))) unsigned*)((char*)Bl + off),
                    16, 0, 0);
            }
        }

        // ---- A: load x, split, swizzled store (2 chunks of 8 per thread) ----
#pragma unroll
        for (int i = 0; i < 2; ++i) {
            const int cid = t * 2 + i;        // 0..1023
            const int r   = cid >> 3;
            const int c   = cid & 7;
            const float* ap = x + (size_t)(bm + r) * 256 + k0 + c * 8;
            float4 v0 = *(const float4*)(ap);
            float4 v1 = *(const float4*)(ap + 4);
            float va[8] = {v0.x, v0.y, v0.z, v0.w, v1.x, v1.y, v1.z, v1.w};
            uint4 hi, lo;
            split8(va, hi, lo);
            const int slot = c ^ (r & 7);
            *(uint4*)&Ah[r * 64 + slot * 8] = hi;
            *(uint4*)&Al[r * 64 + slot * 8] = lo;
        }
        __syncthreads();   // drains gload_lds (vmcnt) + ds_writes

        // ---- MFMA: 2 k-substeps of 32 ----
#pragma unroll
        for (int kk = 0; kk < 2; ++kk) {
            short8 ahf[4], alf[4], bhf[4], blf[4];
#pragma unroll
            for (int mi = 0; mi < 4; ++mi) {
                const int row  = wm * 64 + mi * 16 + lc;
                const int slot = (kk * 4 + g) ^ (row & 7);
                const int off  = row * 64 + slot * 8;
                ahf[mi] = *(const short8*)&Ah[off];
                alf[mi] = *(const short8*)&Al[off];
            }
#pragma unroll
            for (int ni = 0; ni < 4; ++ni) {
                const int row  = wn * 64 + ni * 16 + lc;
                const int slot = (kk * 4 + g) ^ (row & 7);
                const int off  = row * 64 + slot * 8;
                bhf[ni] = *(const short8*)&Bh[off];
                blf[ni] = *(const short8*)&Bl[off];
            }
#pragma unroll
            for (int mi = 0; mi < 4; ++mi)
#pragma unroll
                for (int ni = 0; ni < 4; ++ni) {
                    acc[mi][ni] = __builtin_amdgcn_mfma_f32_16x16x32_bf16(
                        ahf[mi], bhf[ni], acc[mi][ni], 0, 0, 0);
                    acc[mi][ni] = __builtin_amdgcn_mfma_f32_16x16x32_bf16(
                        ahf[mi], blf[ni], acc[mi][ni], 0, 0, 0);
                    acc[mi][ni] = __builtin_amdgcn_mfma_f32_16x16x32_bf16(
                        alf[mi], bhf[ni], acc[mi][ni], 0, 0, 0);
                }
        }
    }

    // ---- epilogue: bias add, store h, per-column stats ----
    float lsum[4] = {0.f, 0.f, 0.f, 0.f};
    float lsq[4]  = {0.f, 0.f, 0.f, 0.f};

#pragma unroll
    for (int mi = 0; mi < 4; ++mi)
#pragma unroll
        for (int ni = 0; ni < 4; ++ni) {
            const int colg = wn * 64 + ni * 16 + lc;
#pragma unroll
            for (int reg = 0; reg < 4; ++reg) {
                const int row = bm + wm * 64 + mi * 16 + g * 4 + reg;
                float hv = acc[mi][ni][reg] + bb[ni];
                h[(size_t)row * 256 + colg] = hv;
                lsum[ni] += hv;
                lsq[ni]   = fmaf(hv, hv, lsq[ni]);
            }
        }

#pragma unroll
    for (int ni = 0; ni < 4; ++ni) {
        lsum[ni] += __shfl_xor(lsum[ni], 16);
        lsum[ni] += __shfl_xor(lsum[ni], 32);
        lsq[ni]  += __shfl_xor(lsq[ni], 16);
        lsq[ni]  += __shfl_xor(lsq[ni], 32);
    }
    if (l < 16) {
#pragma unroll
        for (int ni = 0; ni < 4; ++ni) {
            atomicAdd(&csum[wn * 64 + ni * 16 + lc], lsum[ni]);
            atomicAdd(&csq[wn * 64 + ni * 16 + lc],  lsq[ni]);
        }
    }
    __syncthreads();
    if (t < 256) {
        atomicAdd(&gsum[t], csum[t]);
        atomicAdd(&gsq[t],  csq[t]);
    }
}

// ---------------------------------------------------------------------------
// Kernel 2: finalize BN stats -> per-channel scale a, shift c
// ---------------------------------------------------------------------------
__global__ void k_stats(const float* __restrict__ gsum, const float* __restrict__ gsq,
                        const float* __restrict__ gamma, const float* __restrict__ beta,
                        float* __restrict__ ab)
{
    int j = threadIdx.x;
    float mean = gsum[j] * INV_B;
    float var  = gsq[j] * INV_B - mean * mean;
    float rstd = rsqrtf(var + 1e-5f);
    float a = gamma[j] * rstd;
    ab[j]       = a;
    ab[256 + j] = beta[j] - mean * a;
}

// ---------------------------------------------------------------------------
// Kernel 3: BN+ReLU + MFMA capsule projection + collinear scalar routing.
// (unchanged from R4 — verified; ~5us warm)
// ---------------------------------------------------------------------------
__global__ __launch_bounds__(256) void k_fuse(
    const float* __restrict__ h, const float* __restrict__ ab,
    const float* __restrict__ wc, const float* __restrict__ ow_g,
    const float* __restrict__ ob_g, float* __restrict__ out)
{
    __shared__ ushort Hh[32 * 256];   // 16KB
    __shared__ ushort Hl[32 * 256];   // 16KB
    __shared__ float  us[64 * 68];    // 17KB
    __shared__ float  ows[64];

    const int t   = threadIdx.x;
    const int wid = t >> 6;
    const int l   = t & 63;
    const int g   = l >> 4;           // 0..3
    const int lc  = l & 15;

    if (t < 64) ows[t] = ow_g[t];

    // preload A-frags: A[i][k] = Wc[e=wid][d=k][o=i]
    short8 afh[8], afl[8];
#pragma unroll
    for (int ks = 0; ks < 8; ++ks) {
        union { ushort u16[8]; short8 v; } ph, pl;
#pragma unroll
        for (int j = 0; j < 8; ++j) {
            const int d = ks * 32 + g * 8 + j;
            float wv = wc[wid * 4096 + d * 16 + lc];
            unsigned hh = bf16_rn(wv);
            float res = wv - __uint_as_float(hh << 16);
            ph.u16[j] = (ushort)hh;
            pl.u16[j] = (ushort)bf16_rn(res);
        }
        afh[ks] = ph.v;
        afl[ks] = pl.v;
    }

    const int c8 = (t & 31) * 8;      // staging column group
    float a_[8], cj[8];
    {
        float4 x0 = *(const float4*)(ab + c8);
        float4 x1 = *(const float4*)(ab + c8 + 4);
        float4 y0 = *(const float4*)(ab + 256 + c8);
        float4 y1 = *(const float4*)(ab + 256 + c8 + 4);
        a_[0]=x0.x; a_[1]=x0.y; a_[2]=x0.z; a_[3]=x0.w;
        a_[4]=x1.x; a_[5]=x1.y; a_[6]=x1.z; a_[7]=x1.w;
        cj[0]=y0.x; cj[1]=y0.y; cj[2]=y0.z; cj[3]=y0.w;
        cj[4]=y1.x; cj[5]=y1.y; cj[6]=y1.z; cj[7]=y1.w;
    }

    const int rowBase = (int)blockIdx.x * 64;

#pragma unroll
    for (int sub = 0; sub < 2; ++sub) {
        const int row0 = rowBase + sub * 32;

        __syncthreads();

#pragma unroll
        for (int it = 0; it < 4; ++it) {
            const int r = it * 8 + (t >> 5);          // 0..31
            const float* hp = h + (size_t)(row0 + r) * 256 + c8;
            float4 v0 = *(const float4*)(hp);
            float4 v1 = *(const float4*)(hp + 4);
            float hv[8] = {v0.x, v0.y, v0.z, v0.w, v1.x, v1.y, v1.z, v1.w};
#pragma unroll
            for (int j = 0; j < 8; ++j)
                hv[j] = fmaxf(fmaf(hv[j], a_[j], cj[j]), 0.f);
            uint4 hi, lo;
            split8(hv, hi, lo);
            const int slot = (t & 31) ^ (r & 7);
            *(uint4*)&Hh[r * 256 + slot * 8] = hi;
            *(uint4*)&Hl[r * 256 + slot * 8] = lo;
        }
        __syncthreads();

        f32x4 acc0 = (f32x4){0.f,0.f,0.f,0.f};
        f32x4 acc1 = (f32x4){0.f,0.f,0.f,0.f};
#pragma unroll
        for (int ks = 0; ks < 8; ++ks) {
            {
                const int row  = lc;                   // nt = 0
                const int slot = (ks * 4 + g) ^ (row & 7);
                short8 bh = *(const short8*)&Hh[row * 256 + slot * 8];
                short8 bl = *(const short8*)&Hl[row * 256 + slot * 8];
                acc0 = __builtin_amdgcn_mfma_f32_16x16x32_bf16(afh[ks], bh, acc0, 0,0,0);
                acc0 = __builtin_amdgcn_mfma_f32_16x16x32_bf16(afh[ks], bl, acc0, 0,0,0);
                acc0 = __builtin_amdgcn_mfma_f32_16x16x32_bf16(afl[ks], bh, acc0, 0,0,0);
            }
            {
                const int row  = 16 + lc;              // nt = 1
                const int slot = (ks * 4 + g) ^ (row & 7);
                short8 bh = *(const short8*)&Hh[row * 256 + slot * 8];
                short8 bl = *(const short8*)&Hl[row * 256 + slot * 8];
                acc1 = __builtin_amdgcn_mfma_f32_16x16x32_bf16(afh[ks], bh, acc1, 0,0,0);
                acc1 = __builtin_amdgcn_mfma_f32_16x16x32_bf16(afh[ks], bl, acc1, 0,0,0);
                acc1 = __builtin_amdgcn_mfma_f32_16x16x32_bf16(afl[ks], bh, acc1, 0,0,0);
            }
        }
        {
            const int r0 = sub * 32 + lc;
            *(float4*)&us[r0 * 68 + wid * 16 + g * 4] =
                make_float4(acc0[0], acc0[1], acc0[2], acc0[3]);
            *(float4*)&us[(r0 + 16) * 68 + wid * 16 + g * 4] =
                make_float4(acc1[0], acc1[1], acc1[2], acc1[3]);
        }
    }
    __syncthreads();

    // routing: lane = (row_l = wid*16 + lc, e = g)
    const int row_l = wid * 16 + lc;
    float u[16];
#pragma unroll
    for (int q = 0; q < 4; ++q) {
        float4 v4 = *(const float4*)&us[row_l * 68 + g * 16 + q * 4];
        u[q*4+0] = v4.x; u[q*4+1] = v4.y; u[q*4+2] = v4.z; u[q*4+3] = v4.w;
    }

    float n2 = 0.f;
#pragma unroll
    for (int o = 0; o < 16; ++o) n2 = fmaf(u[o], u[o], n2);
    const float nrm = sqrtf(n2);
    const float sc  = nrm / ((1.f + n2) * (nrm + 1e-8f));  // u_hat = sc*u
    const float nh2 = sc * sc * n2;
    const float nh  = sc * nrm;

    float tk[4];
#pragma unroll
    for (int k = 0; k < 4; ++k) {
        float s = 0.f;
#pragma unroll
        for (int q = 0; q < 4; ++q) {
            float4 w4 = *(const float4*)&ows[k * 16 + q * 4];
            s = fmaf(u[q*4+0], w4.x, s);
            s = fmaf(u[q*4+1], w4.y, s);
            s = fmaf(u[q*4+2], w4.z, s);
            s = fmaf(u[q*4+3], w4.w, s);
        }
        tk[k] = s;
    }

    float b = 0.f, alc = 0.f;
#pragma unroll
    for (int it3 = 0; it3 < 3; ++it3) {
        float bmax = fmaxf(b, __shfl_xor(b, 16));
        bmax = fmaxf(bmax, __shfl_xor(bmax, 32));
        float eb = __expf(b - bmax);
        float es = eb + __shfl_xor(eb, 16);
        es += __shfl_xor(es, 32);
        float c = eb / es;
        float ns  = c * nh;
        float ns2 = c * c * nh2;
        float av  = ns / ((1.f + ns2) * (ns + 1e-8f));
        alc = av * c;
        if (it3 < 2) b += alc * nh2;
    }

    const float vs = alc * sc;
    float p0 = fmaf(vs, tk[0], ob_g[0]);
    float p1 = fmaf(vs, tk[1], ob_g[1]);
    float p2 = fmaf(vs, tk[2], ob_g[2]);
    float p3 = fmaf(vs, tk[3], ob_g[3]);
    float mx = fmaxf(fmaxf(p0, p1), fmaxf(p2, p3));
    float e0 = __expf(p0 - mx), e1 = __expf(p1 - mx);
    float e2 = __expf(p2 - mx), e3 = __expf(p3 - mx);
    float inv = 1.f / (e0 + e1 + e2 + e3);
    *(float4*)&out[(size_t)(rowBase + row_l) * 16 + g * 4] =
        make_float4(e0 * inv, e1 * inv, e2 * inv, e3 * inv);
}

// ---------------------------------------------------------------------------
extern "C" void kernel_launch(void* const* d_in, const int* in_sizes, int n_in,
                              void* d_out, int out_size, void* d_ws, size_t ws_size,
                              hipStream_t stream)
{
    const float* x     = (const float*)d_in[0];
    const float* fc_w  = (const float*)d_in[1];
    const float* fc_b  = (const float*)d_in[2];
    const float* gamma = (const float*)d_in[3];
    const float* beta  = (const float*)d_in[4];
    const float* wc    = (const float*)d_in[5];
    const float* ow    = (const float*)d_in[6];
    const float* ob    = (const float*)d_in[7];
    float* out = (float*)d_out;

    float* gsum = (float*)d_ws;                 // [256]
    float* gsq  = gsum + 256;                   // [256]
    float* ab   = gsum + 512;                   // [512] scale|shift
    float* h    = (float*)((char*)d_ws + 4096); // [131072*256] fp32 = 134MB

    // w-split scratch lives in d_out's first 256KB: written by k_prep, read
    // by k_gemm, then fully overwritten by k_fuse's final output (8MB).
    ushort* wsp = (ushort*)d_out;               // [4][256][64] hi + lo planes

    hipMemsetAsync(d_ws, 0, 2048, stream);      // zero gsum/gsq each call

    k_prep <<<dim3(32),   dim3(256), 0, stream>>>(fc_w, wsp);
    k_gemm <<<dim3(1024), dim3(512), 0, stream>>>(x, wsp, fc_b, h, gsum, gsq);
    k_stats<<<dim3(1),    dim3(256), 0, stream>>>(gsum, gsq, gamma, beta, ab);
    k_fuse <<<dim3(2048), dim3(256), 0, stream>>>(h, ab, wc, ow, ob, out);
}